// Round 3
// baseline (17363.684 us; speedup 1.0000x reference)
//
#include <hip/hip_runtime.h>

// Problem constants (fixed by the reference).
#define NN   50000
#define EE   800000
#define CIN_ 128
#define COUT_ 128
#define HC_  256   // H * COUT

__device__ __forceinline__ float lrelu(float x) { return x >= 0.f ? x : 0.2f * x; }
__device__ __forceinline__ float elu_(float x)  { return x > 0.f ? x : expm1f(x); }

// Fold-to-component extraction: with literal k under #pragma unroll this
// compiles to a plain register move — NO address taken, nothing to scratch.
__device__ __forceinline__ float comp4(const float4& v, int k) {
  return k == 0 ? v.x : k == 1 ? v.y : k == 2 ? v.z : v.w;
}

// ---------------- CSR build ----------------
__global__ void k_hist(const int* __restrict__ dst, int* __restrict__ cnt) {
  int e = blockIdx.x * blockDim.x + threadIdx.x;
  if (e < EE) atomicAdd(&cnt[dst[e]], 1);
}

// Single-block scan: rp[0..N] (exclusive prefix -> rp[i+1]=incl), nxt[i]=excl.
__global__ __launch_bounds__(1024) void k_scan(const int* __restrict__ cnt,
                                               int* __restrict__ rp,
                                               int* __restrict__ nxt, int n) {
  __shared__ int sm[1024];
  int t = threadIdx.x;
  int running = 0;
  if (t == 0) rp[0] = 0;
  for (int base = 0; base < n; base += 8192) {
    int i0 = base + t * 8;
    int v[8]; int s = 0;
#pragma unroll
    for (int q = 0; q < 8; ++q) { v[q] = (i0 + q < n) ? cnt[i0 + q] : 0; s += v[q]; }
    sm[t] = s;
    __syncthreads();
    for (int off = 1; off < 1024; off <<= 1) {
      int add = (t >= off) ? sm[t - off] : 0;
      __syncthreads();
      sm[t] += add;
      __syncthreads();
    }
    int excl = sm[t] - s + running;
    int tot = sm[1023];
    int acc = excl;
#pragma unroll
    for (int q = 0; q < 8; ++q) {
      if (i0 + q < n) { nxt[i0 + q] = acc; rp[i0 + q + 1] = acc + v[q]; }
      acc += v[q];
    }
    running += tot;
    __syncthreads();  // protect sm before next iteration overwrites
  }
}

__global__ void k_fill(const int* __restrict__ src, const int* __restrict__ dst,
                       const float* __restrict__ ea, int* __restrict__ nxt,
                       int* __restrict__ srcS, float* __restrict__ eaS) {
  int e = blockIdx.x * blockDim.x + threadIdx.x;
  if (e >= EE) return;
  int d = dst[e];
  int pos = atomicAdd(&nxt[d], 1);
  srcS[pos] = src[e];
  if (ea) eaS[pos] = ea[e];
}

// ---------------- solo pass: out[n] = sum_{j in CSR(n)} ea_j * x[src_j] ----------------
__global__ __launch_bounds__(256) void k_solo(const int* __restrict__ rp,
                                              const int* __restrict__ srcS,
                                              const float* __restrict__ eaS,
                                              const float* __restrict__ xin,
                                              float* __restrict__ xout) {
  int wid = (blockIdx.x * blockDim.x + threadIdx.x) >> 6;
  int lane = threadIdx.x & 63;
  if (wid >= NN) return;
  int jb = rp[wid], je = rp[wid + 1];
  const int off = lane * 2;
  float2 acc = make_float2(0.f, 0.f);
  int j = jb;
  for (; j + 1 < je; j += 2) {  // 2-way unroll: two independent load chains
    int s0 = srcS[j], s1 = srcS[j + 1];
    float a0 = eaS[j], a1 = eaS[j + 1];
    float2 v0 = *(const float2*)(xin + (size_t)s0 * CIN_ + off);
    float2 v1 = *(const float2*)(xin + (size_t)s1 * CIN_ + off);
    acc.x += a0 * v0.x + a1 * v1.x;
    acc.y += a0 * v0.y + a1 * v1.y;
  }
  if (j < je) {
    int s0 = srcS[j]; float a0 = eaS[j];
    float2 v0 = *(const float2*)(xin + (size_t)s0 * CIN_ + off);
    acc.x += a0 * v0.x; acc.y += a0 * v0.y;
  }
  *(float2*)(xout + (size_t)wid * CIN_ + off) = acc;
}

// ---------------- GEMM1: Hb[N,256] = X[N,128] @ Wg[128,256] ----------------
// 64x64 tile, 256 threads, 4x4 per thread, all-scalar registers (no spill).
__global__ __launch_bounds__(256) void k_gemm1(const float* __restrict__ A,
                                               const float* __restrict__ B,
                                               float* __restrict__ C) {
  __shared__ float As[64][68];  // +4 pad
  __shared__ float Bs[64][64];
  const int t = threadIdx.x;
  const int tx = t & 15, ty = t >> 4;
  const int txc = tx << 2, ty4 = ty << 2;
  const int m0 = blockIdx.x * 64, n0 = blockIdx.y * 64;
  float c00 = 0, c01 = 0, c02 = 0, c03 = 0, c10 = 0, c11 = 0, c12 = 0, c13 = 0,
        c20 = 0, c21 = 0, c22 = 0, c23 = 0, c30 = 0, c31 = 0, c32 = 0, c33 = 0;
  for (int k0 = 0; k0 < CIN_; k0 += 64) {
#pragma unroll
    for (int i = 0; i < 4; ++i) {
      int f = t + i * 256;
      int row = f >> 4, kk = (f & 15) << 2;
      int gm = m0 + row;
      float4 v = make_float4(0.f, 0.f, 0.f, 0.f);
      if (gm < NN) v = *(const float4*)(A + (size_t)gm * CIN_ + k0 + kk);
      *(float4*)&As[row][kk] = v;
    }
#pragma unroll
    for (int i = 0; i < 4; ++i) {
      int f = t + i * 256;
      int kk = f >> 4, nn = (f & 15) << 2;
      *(float4*)&Bs[kk][nn] = *(const float4*)(B + (size_t)(k0 + kk) * HC_ + n0 + nn);
    }
    __syncthreads();
    for (int k4 = 0; k4 < 64; k4 += 4) {
      float4 a0 = *(const float4*)&As[ty4 + 0][k4];
      float4 a1 = *(const float4*)&As[ty4 + 1][k4];
      float4 a2 = *(const float4*)&As[ty4 + 2][k4];
      float4 a3 = *(const float4*)&As[ty4 + 3][k4];
#pragma unroll
      for (int kk = 0; kk < 4; ++kk) {
        float4 b = *(const float4*)&Bs[k4 + kk][txc];
        float w0 = comp4(a0, kk), w1 = comp4(a1, kk);
        float w2 = comp4(a2, kk), w3 = comp4(a3, kk);
        c00 += w0 * b.x; c01 += w0 * b.y; c02 += w0 * b.z; c03 += w0 * b.w;
        c10 += w1 * b.x; c11 += w1 * b.y; c12 += w1 * b.z; c13 += w1 * b.w;
        c20 += w2 * b.x; c21 += w2 * b.y; c22 += w2 * b.z; c23 += w2 * b.w;
        c30 += w3 * b.x; c31 += w3 * b.y; c32 += w3 * b.z; c33 += w3 * b.w;
      }
    }
    __syncthreads();
  }
  {
    int gm = m0 + ty4;
    float* p = C + (size_t)gm * HC_ + n0 + txc;
    if (gm + 0 < NN) *(float4*)(p + 0 * HC_) = make_float4(c00, c01, c02, c03);
    if (gm + 1 < NN) *(float4*)(p + 1 * HC_) = make_float4(c10, c11, c12, c13);
    if (gm + 2 < NN) *(float4*)(p + 2 * HC_) = make_float4(c20, c21, c22, c23);
    if (gm + 3 < NN) *(float4*)(p + 3 * HC_) = make_float4(c30, c31, c32, c33);
  }
}

// ---------------- attn coefficients: AS/AD[n,h] = sum_c Hb[n,h,c]*att[h,c] ----------------
__global__ __launch_bounds__(256) void k_attn(const float* __restrict__ Hb,
                                              const float* __restrict__ att_s,
                                              const float* __restrict__ att_d,
                                              float* __restrict__ AS, float* __restrict__ AD) {
  int wid = (blockIdx.x * blockDim.x + threadIdx.x) >> 6;
  int lane = threadIdx.x & 63;
  if (wid >= NN) return;
  int c = lane << 2;  // lanes 0..31 -> head0 (c<128), 32..63 -> head1
  float4 h4 = *(const float4*)(Hb + (size_t)wid * HC_ + c);
  float4 s4 = *(const float4*)(att_s + c);
  float4 d4 = *(const float4*)(att_d + c);
  float ps = h4.x * s4.x + h4.y * s4.y + h4.z * s4.z + h4.w * s4.w;
  float pd = h4.x * d4.x + h4.y * d4.y + h4.z * d4.z + h4.w * d4.w;
#pragma unroll
  for (int d = 1; d < 32; d <<= 1) {  // reduce within each 32-lane half
    ps += __shfl_xor(ps, d, 64);
    pd += __shfl_xor(pd, d, 64);
  }
  if (lane == 0)  { AS[wid * 2 + 0] = ps; AD[wid * 2 + 0] = pd; }
  if (lane == 32) { AS[wid * 2 + 1] = ps; AD[wid * 2 + 1] = pd; }
}

// ---------------- GAT: per-node wave does max -> denom -> weighted gather ----------------
__global__ __launch_bounds__(256) void k_gat(const int* __restrict__ rp,
                                             const int* __restrict__ srcO,
                                             const float* __restrict__ AS,
                                             const float* __restrict__ AD,
                                             const float* __restrict__ Hb,
                                             float* __restrict__ Eb,
                                             float* __restrict__ G) {
  int wid = (blockIdx.x * blockDim.x + threadIdx.x) >> 6;
  int lane = threadIdx.x & 63;
  if (wid >= NN) return;
  int jb = rp[wid], je = rp[wid + 1];
  float2 adn = *(const float2*)(AD + 2 * (size_t)wid);
  float2 asn = *(const float2*)(AS + 2 * (size_t)wid);
  float le0 = lrelu(asn.x + adn.x), le1 = lrelu(asn.y + adn.y);  // self-loop e
  float m0 = le0, m1 = le1;
  // phase 1: e per edge + running max (lane-strided)
  for (int j = jb + lane; j < je; j += 64) {
    int s = srcO[j];
    float2 av = *(const float2*)(AS + 2 * (size_t)s);
    float e0 = lrelu(av.x + adn.x), e1 = lrelu(av.y + adn.y);
    *(float2*)(Eb + 2 * (size_t)j) = make_float2(e0, e1);
    m0 = fmaxf(m0, e0); m1 = fmaxf(m1, e1);
  }
#pragma unroll
  for (int d = 1; d < 64; d <<= 1) {
    m0 = fmaxf(m0, __shfl_xor(m0, d, 64));
    m1 = fmaxf(m1, __shfl_xor(m1, d, 64));
  }
  // phase 2: denom; rewrite Eb with exp(e-m)
  float s0 = 0.f, s1 = 0.f;
  if (lane == 0) { s0 = expf(le0 - m0); s1 = expf(le1 - m1); }  // loop term once
  for (int j = jb + lane; j < je; j += 64) {
    float2 e = *(const float2*)(Eb + 2 * (size_t)j);
    float a0 = expf(e.x - m0), a1 = expf(e.y - m1);
    *(float2*)(Eb + 2 * (size_t)j) = make_float2(a0, a1);
    s0 += a0; s1 += a1;
  }
#pragma unroll
  for (int d = 1; d < 64; d <<= 1) {
    s0 += __shfl_xor(s0, d, 64);
    s1 += __shfl_xor(s1, d, 64);
  }
  float inv0 = 1.f / (s0 + 1e-16f), inv1 = 1.f / (s1 + 1e-16f);
  __threadfence_block();  // phase-2 Eb writes -> phase-3 cross-lane reads
  // phase 3: G[n] = alpha_loop*h[n] + sum_j alpha_j*h[src_j]; lane covers 4 ch
  int ccol = lane << 2;
  bool h0 = lane < 32;
  float la = h0 ? expf(le0 - m0) * inv0 : expf(le1 - m1) * inv1;
  float4 hv = *(const float4*)(Hb + (size_t)wid * HC_ + ccol);
  float4 acc = make_float4(la * hv.x, la * hv.y, la * hv.z, la * hv.w);
  int j = jb;
  for (; j + 1 < je; j += 2) {
    int sA = srcO[j], sB = srcO[j + 1];
    float2 aA = *(const float2*)(Eb + 2 * (size_t)j);
    float2 aB = *(const float2*)(Eb + 2 * (size_t)(j + 1));
    float4 hA = *(const float4*)(Hb + (size_t)sA * HC_ + ccol);
    float4 hB = *(const float4*)(Hb + (size_t)sB * HC_ + ccol);
    float wA = h0 ? aA.x * inv0 : aA.y * inv1;
    float wB = h0 ? aB.x * inv0 : aB.y * inv1;
    acc.x += wA * hA.x + wB * hB.x; acc.y += wA * hA.y + wB * hB.y;
    acc.z += wA * hA.z + wB * hB.z; acc.w += wA * hA.w + wB * hB.w;
  }
  if (j < je) {
    int sA = srcO[j];
    float2 aA = *(const float2*)(Eb + 2 * (size_t)j);
    float4 hA = *(const float4*)(Hb + (size_t)sA * HC_ + ccol);
    float wA = h0 ? aA.x * inv0 : aA.y * inv1;
    acc.x += wA * hA.x; acc.y += wA * hA.y; acc.z += wA * hA.z; acc.w += wA * hA.w;
  }
  *(float4*)(G + (size_t)wid * HC_ + ccol) = acc;
}

// ---------------- GEMM2: Z[N,128] = ELU(G+gb)[N,256] @ lw[256,128] + lb; BN stats ----------------
__global__ __launch_bounds__(256) void k_gemm2(const float* __restrict__ Gm,
                                               const float* __restrict__ gb,
                                               const float* __restrict__ B,
                                               const float* __restrict__ lb,
                                               float* __restrict__ Z,
                                               double* __restrict__ gS,
                                               double* __restrict__ gQ) {
  __shared__ float As[64][68];
  __shared__ float Bs[64][64];
  __shared__ float colS[64], colQ[64];
  const int t = threadIdx.x;
  const int tx = t & 15, ty = t >> 4;
  const int txc = tx << 2, ty4 = ty << 2;
  const int m0 = blockIdx.x * 64, n0 = blockIdx.y * 64;
  float c00 = 0, c01 = 0, c02 = 0, c03 = 0, c10 = 0, c11 = 0, c12 = 0, c13 = 0,
        c20 = 0, c21 = 0, c22 = 0, c23 = 0, c30 = 0, c31 = 0, c32 = 0, c33 = 0;
  for (int k0 = 0; k0 < HC_; k0 += 64) {
#pragma unroll
    for (int i = 0; i < 4; ++i) {
      int f = t + i * 256;
      int row = f >> 4, kk = (f & 15) << 2;
      int gm = m0 + row;
      float4 v = make_float4(0.f, 0.f, 0.f, 0.f);
      if (gm < NN) {
        float4 g4 = *(const float4*)(Gm + (size_t)gm * HC_ + k0 + kk);
        float4 b4 = *(const float4*)(gb + k0 + kk);
        v.x = elu_(g4.x + b4.x); v.y = elu_(g4.y + b4.y);
        v.z = elu_(g4.z + b4.z); v.w = elu_(g4.w + b4.w);
      }
      *(float4*)&As[row][kk] = v;
    }
#pragma unroll
    for (int i = 0; i < 4; ++i) {
      int f = t + i * 256;
      int kk = f >> 4, nn = (f & 15) << 2;
      *(float4*)&Bs[kk][nn] = *(const float4*)(B + (size_t)(k0 + kk) * COUT_ + n0 + nn);
    }
    __syncthreads();
    for (int k4 = 0; k4 < 64; k4 += 4) {
      float4 a0 = *(const float4*)&As[ty4 + 0][k4];
      float4 a1 = *(const float4*)&As[ty4 + 1][k4];
      float4 a2 = *(const float4*)&As[ty4 + 2][k4];
      float4 a3 = *(const float4*)&As[ty4 + 3][k4];
#pragma unroll
      for (int kk = 0; kk < 4; ++kk) {
        float4 b = *(const float4*)&Bs[k4 + kk][txc];
        float w0 = comp4(a0, kk), w1 = comp4(a1, kk);
        float w2 = comp4(a2, kk), w3 = comp4(a3, kk);
        c00 += w0 * b.x; c01 += w0 * b.y; c02 += w0 * b.z; c03 += w0 * b.w;
        c10 += w1 * b.x; c11 += w1 * b.y; c12 += w1 * b.z; c13 += w1 * b.w;
        c20 += w2 * b.x; c21 += w2 * b.y; c22 += w2 * b.z; c23 += w2 * b.w;
        c30 += w3 * b.x; c31 += w3 * b.y; c32 += w3 * b.z; c33 += w3 * b.w;
      }
    }
    __syncthreads();
  }
  // epilogue: +lb, store Z, accumulate column sums/sumsq (guard tail rows!)
  float4 lb4 = *(const float4*)(lb + n0 + txc);
  if (t < 64) { colS[t] = 0.f; colQ[t] = 0.f; }
  __syncthreads();
  float ps0 = 0, ps1 = 0, ps2 = 0, ps3 = 0, pq0 = 0, pq1 = 0, pq2 = 0, pq3 = 0;
  {
    int gm = m0 + ty4;
    float* p = Z + (size_t)gm * COUT_ + n0 + txc;
#define ROW_EP(CA, CB, CC, CD, R)                                              \
    if (gm + R < NN) {                                                         \
      float z0 = CA + lb4.x, z1 = CB + lb4.y, z2 = CC + lb4.z, z3 = CD + lb4.w;\
      *(float4*)(p + R * COUT_) = make_float4(z0, z1, z2, z3);                 \
      ps0 += z0; ps1 += z1; ps2 += z2; ps3 += z3;                              \
      pq0 += z0 * z0; pq1 += z1 * z1; pq2 += z2 * z2; pq3 += z3 * z3;          \
    }
    ROW_EP(c00, c01, c02, c03, 0)
    ROW_EP(c10, c11, c12, c13, 1)
    ROW_EP(c20, c21, c22, c23, 2)
    ROW_EP(c30, c31, c32, c33, 3)
#undef ROW_EP
  }
  atomicAdd(&colS[txc + 0], ps0); atomicAdd(&colQ[txc + 0], pq0);
  atomicAdd(&colS[txc + 1], ps1); atomicAdd(&colQ[txc + 1], pq1);
  atomicAdd(&colS[txc + 2], ps2); atomicAdd(&colQ[txc + 2], pq2);
  atomicAdd(&colS[txc + 3], ps3); atomicAdd(&colQ[txc + 3], pq3);
  __syncthreads();
  if (t < 64) {
    atomicAdd(&gS[n0 + t], (double)colS[t]);
    atomicAdd(&gQ[n0 + t], (double)colQ[t]);
  }
}

// ---------------- BN finalize + accumulate into out ----------------
__global__ void k_bn(const float* __restrict__ Z, const double* __restrict__ gS,
                     const double* __restrict__ gQ, const float* __restrict__ gamma,
                     const float* __restrict__ beta, float* __restrict__ out) {
  int i = blockIdx.x * blockDim.x + threadIdx.x;
  if (i >= NN * COUT_) return;
  int cc = i & (COUT_ - 1);
  double mu = gS[cc] * (1.0 / NN);
  double var = gQ[cc] * (1.0 / NN) - mu * mu;
  float inv = (float)(1.0 / sqrt(var + 1e-5));
  out[i] += gamma[cc] * (Z[i] - (float)mu) * inv + beta[cc];
}

extern "C" void kernel_launch(void* const* d_in, const int* in_sizes, int n_in,
                              void* d_out, int out_size, void* d_ws, size_t ws_size,
                              hipStream_t stream) {
  const float* x     = (const float*)d_in[0];
  const int*   eiO   = (const int*)d_in[1];
  const float* Wg    = (const float*)d_in[2];
  const float* atts  = (const float*)d_in[3];
  const float* attd  = (const float*)d_in[4];
  const float* gb    = (const float*)d_in[5];
  const float* lw    = (const float*)d_in[6];
  const float* lb    = (const float*)d_in[7];
  const float* gamma = (const float*)d_in[8];
  const float* beta  = (const float*)d_in[9];
  const int*   sei[4] = {(const int*)d_in[10], (const int*)d_in[12],
                         (const int*)d_in[14], (const int*)d_in[16]};
  const float* sea[4] = {(const float*)d_in[11], (const float*)d_in[13],
                         (const float*)d_in[15], (const float*)d_in[17]};
  float* out = (float*)d_out;

  // ---- workspace carve (~205 MB) ----
  char* w = (char*)d_ws;
  auto take = [&](size_t bytes) -> void* {
    void* p = (void*)w;
    w += (bytes + 255) & ~(size_t)255;
    return p;
  };
  int*    rp0   = (int*)take((NN + 1) * sizeof(int));
  int*    nxt   = (int*)take(NN * sizeof(int));
  int*    cnt   = (int*)take(NN * sizeof(int));
  int*    srcS0 = (int*)take(EE * sizeof(int));
  float*  eaS0  = (float*)take(EE * sizeof(float));
  int*    rpT   = (int*)take((NN + 1) * sizeof(int));
  int*    srcST = (int*)take(EE * sizeof(int));
  float*  eaST  = (float*)take(EE * sizeof(float));
  int*    rpO   = (int*)take((NN + 1) * sizeof(int));
  int*    srcO  = (int*)take(EE * sizeof(int));
  float*  T     = (float*)take((size_t)NN * CIN_ * sizeof(float));
  float*  X     = (float*)take((size_t)NN * CIN_ * sizeof(float));
  float*  Hb    = (float*)take((size_t)NN * HC_ * sizeof(float));
  float*  G     = (float*)take((size_t)NN * HC_ * sizeof(float));
  float*  Z     = (float*)take((size_t)NN * COUT_ * sizeof(float));
  float*  ASb   = (float*)take((size_t)NN * 2 * sizeof(float));
  float*  ADb   = (float*)take((size_t)NN * 2 * sizeof(float));
  float*  Eb    = (float*)take((size_t)EE * 2 * sizeof(float));
  double* gS    = (double*)take(256 * sizeof(double));
  double* gQ    = gS + 128;

  const int EB = (EE + 255) / 256;   // edge-grid blocks
  const int NW = (NN + 3) / 4;       // node-wave blocks (4 waves of 64 per block)
  const int MB = (NN + 63) / 64;     // GEMM row tiles = 782

  (void)hipMemsetAsync(d_out, 0, (size_t)NN * COUT_ * sizeof(float), stream);

  // CSR for sei0 (reused 4x) and for edge_index_o (reused 4x)
  (void)hipMemsetAsync(cnt, 0, NN * sizeof(int), stream);
  k_hist<<<EB, 256, 0, stream>>>(sei[0] + EE, cnt);
  k_scan<<<1, 1024, 0, stream>>>(cnt, rp0, nxt, NN);
  k_fill<<<EB, 256, 0, stream>>>(sei[0], sei[0] + EE, sea[0], nxt, srcS0, eaS0);

  (void)hipMemsetAsync(cnt, 0, NN * sizeof(int), stream);
  k_hist<<<EB, 256, 0, stream>>>(eiO + EE, cnt);
  k_scan<<<1, 1024, 0, stream>>>(cnt, rpO, nxt, NN);
  k_fill<<<EB, 256, 0, stream>>>(eiO, eiO + EE, (const float*)nullptr, nxt, srcO, (float*)nullptr);

  for (int g = 0; g < 4; ++g) {
    if (g == 0) {
      k_solo<<<NW, 256, 0, stream>>>(rp0, srcS0, eaS0, x, X);
    } else {
      (void)hipMemsetAsync(cnt, 0, NN * sizeof(int), stream);
      k_hist<<<EB, 256, 0, stream>>>(sei[g] + EE, cnt);
      k_scan<<<1, 1024, 0, stream>>>(cnt, rpT, nxt, NN);
      k_fill<<<EB, 256, 0, stream>>>(sei[g], sei[g] + EE, sea[g], nxt, srcST, eaST);
      k_solo<<<NW, 256, 0, stream>>>(rpT, srcST, eaST, x, T);   // xh_g = S_g(x)
      k_solo<<<NW, 256, 0, stream>>>(rp0, srcS0, eaS0, T, X);   // x_g = S_0(xh_g)
    }
    k_gemm1<<<dim3(MB, 4), 256, 0, stream>>>(X, Wg + (size_t)g * CIN_ * HC_, Hb);
    k_attn<<<NW, 256, 0, stream>>>(Hb, atts + (size_t)g * HC_, attd + (size_t)g * HC_, ASb, ADb);
    k_gat<<<NW, 256, 0, stream>>>(rpO, srcO, ASb, ADb, Hb, Eb, G);
    (void)hipMemsetAsync(gS, 0, 256 * sizeof(double), stream);
    k_gemm2<<<dim3(MB, 2), 256, 0, stream>>>(G, gb + (size_t)g * HC_,
                                             lw + (size_t)g * HC_ * COUT_,
                                             lb + (size_t)g * COUT_, Z, gS, gQ);
    k_bn<<<(NN * COUT_ + 255) / 256, 256, 0, stream>>>(Z, gS, gQ,
                                                       gamma + (size_t)g * COUT_,
                                                       beta + (size_t)g * COUT_, out);
  }
}

// Round 4
// 2574.350 us; speedup vs baseline: 6.7449x; 6.7449x over previous
//
#include <hip/hip_runtime.h>

// Problem constants (fixed by the reference).
#define NN   50000
#define EE   800000
#define CIN_ 128
#define COUT_ 128
#define HC_  256   // H * COUT

__device__ __forceinline__ float lrelu(float x) { return x >= 0.f ? x : 0.2f * x; }
__device__ __forceinline__ float elu_(float x)  { return x > 0.f ? x : expm1f(x); }

// Fold-to-component extraction (by VALUE — no address, no reference).
__device__ __forceinline__ float comp4(float4 v, int k) {
  return k == 0 ? v.x : k == 1 ? v.y : k == 2 ? v.z : v.w;
}

// ---------------- CSR build ----------------
__global__ void k_hist(const int* __restrict__ dst, int* __restrict__ cnt) {
  int e = blockIdx.x * blockDim.x + threadIdx.x;
  if (e < EE) atomicAdd(&cnt[dst[e]], 1);
}

// Single-block scan: rp[0..N] (exclusive prefix -> rp[i+1]=incl), nxt[i]=excl.
__global__ __launch_bounds__(1024) void k_scan(const int* __restrict__ cnt,
                                               int* __restrict__ rp,
                                               int* __restrict__ nxt, int n) {
  __shared__ int sm[1024];
  int t = threadIdx.x;
  int running = 0;
  if (t == 0) rp[0] = 0;
  for (int base = 0; base < n; base += 8192) {
    int i0 = base + t * 8;
    int v[8]; int s = 0;
#pragma unroll
    for (int q = 0; q < 8; ++q) { v[q] = (i0 + q < n) ? cnt[i0 + q] : 0; s += v[q]; }
    sm[t] = s;
    __syncthreads();
    for (int off = 1; off < 1024; off <<= 1) {
      int add = (t >= off) ? sm[t - off] : 0;
      __syncthreads();
      sm[t] += add;
      __syncthreads();
    }
    int excl = sm[t] - s + running;
    int tot = sm[1023];
    int acc = excl;
#pragma unroll
    for (int q = 0; q < 8; ++q) {
      if (i0 + q < n) { nxt[i0 + q] = acc; rp[i0 + q + 1] = acc + v[q]; }
      acc += v[q];
    }
    running += tot;
    __syncthreads();  // protect sm before next iteration overwrites
  }
}

__global__ void k_fill(const int* __restrict__ src, const int* __restrict__ dst,
                       const float* __restrict__ ea, int* __restrict__ nxt,
                       int* __restrict__ srcS, float* __restrict__ eaS) {
  int e = blockIdx.x * blockDim.x + threadIdx.x;
  if (e >= EE) return;
  int d = dst[e];
  int pos = atomicAdd(&nxt[d], 1);
  srcS[pos] = src[e];
  if (ea) eaS[pos] = ea[e];
}

// ---------------- solo pass: out[n] = sum_{j in CSR(n)} ea_j * x[src_j] ----------------
__global__ __launch_bounds__(256) void k_solo(const int* __restrict__ rp,
                                              const int* __restrict__ srcS,
                                              const float* __restrict__ eaS,
                                              const float* __restrict__ xin,
                                              float* __restrict__ xout) {
  int wid = (blockIdx.x * blockDim.x + threadIdx.x) >> 6;
  int lane = threadIdx.x & 63;
  if (wid >= NN) return;
  int jb = rp[wid], je = rp[wid + 1];
  const int off = lane * 2;
  float2 acc = make_float2(0.f, 0.f);
  int j = jb;
  for (; j + 1 < je; j += 2) {  // 2-way unroll: two independent load chains
    int s0 = srcS[j], s1 = srcS[j + 1];
    float a0 = eaS[j], a1 = eaS[j + 1];
    float2 v0 = *(const float2*)(xin + (size_t)s0 * CIN_ + off);
    float2 v1 = *(const float2*)(xin + (size_t)s1 * CIN_ + off);
    acc.x += a0 * v0.x + a1 * v1.x;
    acc.y += a0 * v0.y + a1 * v1.y;
  }
  if (j < je) {
    int s0 = srcS[j]; float a0 = eaS[j];
    float2 v0 = *(const float2*)(xin + (size_t)s0 * CIN_ + off);
    acc.x += a0 * v0.x; acc.y += a0 * v0.y;
  }
  *(float2*)(xout + (size_t)wid * CIN_ + off) = acc;
}

// ---------------- GEMM1: Hb[N,256] = X[N,128] @ Wg[128,256] ----------------
// 64x64 tile, 256 threads, 4x4/thread. launch_bounds(...,2) caps VGPR at 128
// so the scheduler cannot hoist 16 k-steps of LDS reads (the round-3 spill).
__global__ __launch_bounds__(256, 2) void k_gemm1(const float* __restrict__ A,
                                                  const float* __restrict__ B,
                                                  float* __restrict__ C) {
  __shared__ float As[64][68];  // +4 pad
  __shared__ float Bs[64][64];
  const int t = threadIdx.x;
  const int tx = t & 15, ty = t >> 4;
  const int txc = tx << 2, ty4 = ty << 2;
  const int m0 = blockIdx.x * 64, n0 = blockIdx.y * 64;
  float c00 = 0, c01 = 0, c02 = 0, c03 = 0, c10 = 0, c11 = 0, c12 = 0, c13 = 0,
        c20 = 0, c21 = 0, c22 = 0, c23 = 0, c30 = 0, c31 = 0, c32 = 0, c33 = 0;
#pragma unroll 1
  for (int k0 = 0; k0 < CIN_; k0 += 64) {
#pragma unroll
    for (int i = 0; i < 4; ++i) {
      int f = t + i * 256;
      int row = f >> 4, kk = (f & 15) << 2;
      int gm = m0 + row;
      float4 v = make_float4(0.f, 0.f, 0.f, 0.f);
      if (gm < NN) v = *(const float4*)(A + (size_t)gm * CIN_ + k0 + kk);
      *(float4*)&As[row][kk] = v;
    }
#pragma unroll
    for (int i = 0; i < 4; ++i) {
      int f = t + i * 256;
      int kk = f >> 4, nn = (f & 15) << 2;
      *(float4*)&Bs[kk][nn] = *(const float4*)(B + (size_t)(k0 + kk) * HC_ + n0 + nn);
    }
    __syncthreads();
#pragma unroll 2
    for (int k4 = 0; k4 < 64; k4 += 4) {
      float4 a0 = *(const float4*)&As[ty4 + 0][k4];
      float4 a1 = *(const float4*)&As[ty4 + 1][k4];
      float4 a2 = *(const float4*)&As[ty4 + 2][k4];
      float4 a3 = *(const float4*)&As[ty4 + 3][k4];
#pragma unroll
      for (int kk = 0; kk < 4; ++kk) {
        float4 b = *(const float4*)&Bs[k4 + kk][txc];
        float w0 = comp4(a0, kk), w1 = comp4(a1, kk);
        float w2 = comp4(a2, kk), w3 = comp4(a3, kk);
        c00 += w0 * b.x; c01 += w0 * b.y; c02 += w0 * b.z; c03 += w0 * b.w;
        c10 += w1 * b.x; c11 += w1 * b.y; c12 += w1 * b.z; c13 += w1 * b.w;
        c20 += w2 * b.x; c21 += w2 * b.y; c22 += w2 * b.z; c23 += w2 * b.w;
        c30 += w3 * b.x; c31 += w3 * b.y; c32 += w3 * b.z; c33 += w3 * b.w;
      }
    }
    __syncthreads();
  }
  {
    int gm = m0 + ty4;
    float* p = C + (size_t)gm * HC_ + n0 + txc;
    if (gm + 0 < NN) *(float4*)(p + 0 * HC_) = make_float4(c00, c01, c02, c03);
    if (gm + 1 < NN) *(float4*)(p + 1 * HC_) = make_float4(c10, c11, c12, c13);
    if (gm + 2 < NN) *(float4*)(p + 2 * HC_) = make_float4(c20, c21, c22, c23);
    if (gm + 3 < NN) *(float4*)(p + 3 * HC_) = make_float4(c30, c31, c32, c33);
  }
}

// ---------------- attn coefficients: AS/AD[n,h] = sum_c Hb[n,h,c]*att[h,c] ----------------
__global__ __launch_bounds__(256) void k_attn(const float* __restrict__ Hb,
                                              const float* __restrict__ att_s,
                                              const float* __restrict__ att_d,
                                              float* __restrict__ AS, float* __restrict__ AD) {
  int wid = (blockIdx.x * blockDim.x + threadIdx.x) >> 6;
  int lane = threadIdx.x & 63;
  if (wid >= NN) return;
  int c = lane << 2;  // lanes 0..31 -> head0 (c<128), 32..63 -> head1
  float4 h4 = *(const float4*)(Hb + (size_t)wid * HC_ + c);
  float4 s4 = *(const float4*)(att_s + c);
  float4 d4 = *(const float4*)(att_d + c);
  float ps = h4.x * s4.x + h4.y * s4.y + h4.z * s4.z + h4.w * s4.w;
  float pd = h4.x * d4.x + h4.y * d4.y + h4.z * d4.z + h4.w * d4.w;
#pragma unroll
  for (int d = 1; d < 32; d <<= 1) {  // reduce within each 32-lane half
    ps += __shfl_xor(ps, d, 64);
    pd += __shfl_xor(pd, d, 64);
  }
  if (lane == 0)  { AS[wid * 2 + 0] = ps; AD[wid * 2 + 0] = pd; }
  if (lane == 32) { AS[wid * 2 + 1] = ps; AD[wid * 2 + 1] = pd; }
}

// ---------------- GAT: per-node wave does max -> denom -> weighted gather ----------------
__global__ __launch_bounds__(256) void k_gat(const int* __restrict__ rp,
                                             const int* __restrict__ srcO,
                                             const float* __restrict__ AS,
                                             const float* __restrict__ AD,
                                             const float* __restrict__ Hb,
                                             float* __restrict__ Eb,
                                             float* __restrict__ G) {
  int wid = (blockIdx.x * blockDim.x + threadIdx.x) >> 6;
  int lane = threadIdx.x & 63;
  if (wid >= NN) return;
  int jb = rp[wid], je = rp[wid + 1];
  float2 adn = *(const float2*)(AD + 2 * (size_t)wid);
  float2 asn = *(const float2*)(AS + 2 * (size_t)wid);
  float le0 = lrelu(asn.x + adn.x), le1 = lrelu(asn.y + adn.y);  // self-loop e
  float m0 = le0, m1 = le1;
  // phase 1: e per edge + running max (lane-strided)
  for (int j = jb + lane; j < je; j += 64) {
    int s = srcO[j];
    float2 av = *(const float2*)(AS + 2 * (size_t)s);
    float e0 = lrelu(av.x + adn.x), e1 = lrelu(av.y + adn.y);
    *(float2*)(Eb + 2 * (size_t)j) = make_float2(e0, e1);
    m0 = fmaxf(m0, e0); m1 = fmaxf(m1, e1);
  }
#pragma unroll
  for (int d = 1; d < 64; d <<= 1) {
    m0 = fmaxf(m0, __shfl_xor(m0, d, 64));
    m1 = fmaxf(m1, __shfl_xor(m1, d, 64));
  }
  // phase 2: denom; rewrite Eb with exp(e-m)
  float s0 = 0.f, s1 = 0.f;
  if (lane == 0) { s0 = expf(le0 - m0); s1 = expf(le1 - m1); }  // loop term once
  for (int j = jb + lane; j < je; j += 64) {
    float2 e = *(const float2*)(Eb + 2 * (size_t)j);
    float a0 = expf(e.x - m0), a1 = expf(e.y - m1);
    *(float2*)(Eb + 2 * (size_t)j) = make_float2(a0, a1);
    s0 += a0; s1 += a1;
  }
#pragma unroll
  for (int d = 1; d < 64; d <<= 1) {
    s0 += __shfl_xor(s0, d, 64);
    s1 += __shfl_xor(s1, d, 64);
  }
  float inv0 = 1.f / (s0 + 1e-16f), inv1 = 1.f / (s1 + 1e-16f);
  __threadfence_block();  // phase-2 Eb writes -> phase-3 cross-lane reads
  // phase 3: G[n] = alpha_loop*h[n] + sum_j alpha_j*h[src_j]; lane covers 4 ch
  int ccol = lane << 2;
  bool h0 = lane < 32;
  float la = h0 ? expf(le0 - m0) * inv0 : expf(le1 - m1) * inv1;
  float4 hv = *(const float4*)(Hb + (size_t)wid * HC_ + ccol);
  float4 acc = make_float4(la * hv.x, la * hv.y, la * hv.z, la * hv.w);
  int j = jb;
  for (; j + 1 < je; j += 2) {
    int sA = srcO[j], sB = srcO[j + 1];
    float2 aA = *(const float2*)(Eb + 2 * (size_t)j);
    float2 aB = *(const float2*)(Eb + 2 * (size_t)(j + 1));
    float4 hA = *(const float4*)(Hb + (size_t)sA * HC_ + ccol);
    float4 hB = *(const float4*)(Hb + (size_t)sB * HC_ + ccol);
    float wA = h0 ? aA.x * inv0 : aA.y * inv1;
    float wB = h0 ? aB.x * inv0 : aB.y * inv1;
    acc.x += wA * hA.x + wB * hB.x; acc.y += wA * hA.y + wB * hB.y;
    acc.z += wA * hA.z + wB * hB.z; acc.w += wA * hA.w + wB * hB.w;
  }
  if (j < je) {
    int sA = srcO[j];
    float2 aA = *(const float2*)(Eb + 2 * (size_t)j);
    float4 hA = *(const float4*)(Hb + (size_t)sA * HC_ + ccol);
    float wA = h0 ? aA.x * inv0 : aA.y * inv1;
    acc.x += wA * hA.x; acc.y += wA * hA.y; acc.z += wA * hA.z; acc.w += wA * hA.w;
  }
  *(float4*)(G + (size_t)wid * HC_ + ccol) = acc;
}

// ---------------- GEMM2: Z[N,128] = ELU(G+gb)[N,256] @ lw[256,128] + lb; BN stats ----------------
__global__ __launch_bounds__(256, 2) void k_gemm2(const float* __restrict__ Gm,
                                                  const float* __restrict__ gb,
                                                  const float* __restrict__ B,
                                                  const float* __restrict__ lb,
                                                  float* __restrict__ Z,
                                                  double* __restrict__ gS,
                                                  double* __restrict__ gQ) {
  __shared__ float As[64][68];
  __shared__ float Bs[64][64];
  __shared__ float colS[64], colQ[64];
  const int t = threadIdx.x;
  const int tx = t & 15, ty = t >> 4;
  const int txc = tx << 2, ty4 = ty << 2;
  const int m0 = blockIdx.x * 64, n0 = blockIdx.y * 64;
  float c00 = 0, c01 = 0, c02 = 0, c03 = 0, c10 = 0, c11 = 0, c12 = 0, c13 = 0,
        c20 = 0, c21 = 0, c22 = 0, c23 = 0, c30 = 0, c31 = 0, c32 = 0, c33 = 0;
#pragma unroll 1
  for (int k0 = 0; k0 < HC_; k0 += 64) {
#pragma unroll
    for (int i = 0; i < 4; ++i) {
      int f = t + i * 256;
      int row = f >> 4, kk = (f & 15) << 2;
      int gm = m0 + row;
      float4 v = make_float4(0.f, 0.f, 0.f, 0.f);
      if (gm < NN) {
        float4 g4 = *(const float4*)(Gm + (size_t)gm * HC_ + k0 + kk);
        float4 b4 = *(const float4*)(gb + k0 + kk);
        v.x = elu_(g4.x + b4.x); v.y = elu_(g4.y + b4.y);
        v.z = elu_(g4.z + b4.z); v.w = elu_(g4.w + b4.w);
      }
      *(float4*)&As[row][kk] = v;
    }
#pragma unroll
    for (int i = 0; i < 4; ++i) {
      int f = t + i * 256;
      int kk = f >> 4, nn = (f & 15) << 2;
      *(float4*)&Bs[kk][nn] = *(const float4*)(B + (size_t)(k0 + kk) * COUT_ + n0 + nn);
    }
    __syncthreads();
#pragma unroll 2
    for (int k4 = 0; k4 < 64; k4 += 4) {
      float4 a0 = *(const float4*)&As[ty4 + 0][k4];
      float4 a1 = *(const float4*)&As[ty4 + 1][k4];
      float4 a2 = *(const float4*)&As[ty4 + 2][k4];
      float4 a3 = *(const float4*)&As[ty4 + 3][k4];
#pragma unroll
      for (int kk = 0; kk < 4; ++kk) {
        float4 b = *(const float4*)&Bs[k4 + kk][txc];
        float w0 = comp4(a0, kk), w1 = comp4(a1, kk);
        float w2 = comp4(a2, kk), w3 = comp4(a3, kk);
        c00 += w0 * b.x; c01 += w0 * b.y; c02 += w0 * b.z; c03 += w0 * b.w;
        c10 += w1 * b.x; c11 += w1 * b.y; c12 += w1 * b.z; c13 += w1 * b.w;
        c20 += w2 * b.x; c21 += w2 * b.y; c22 += w2 * b.z; c23 += w2 * b.w;
        c30 += w3 * b.x; c31 += w3 * b.y; c32 += w3 * b.z; c33 += w3 * b.w;
      }
    }
    __syncthreads();
  }
  // epilogue: +lb, store Z, accumulate column sums/sumsq (guard tail rows!)
  float4 lb4 = *(const float4*)(lb + n0 + txc);
  if (t < 64) { colS[t] = 0.f; colQ[t] = 0.f; }
  __syncthreads();
  float ps0 = 0, ps1 = 0, ps2 = 0, ps3 = 0, pq0 = 0, pq1 = 0, pq2 = 0, pq3 = 0;
  {
    int gm = m0 + ty4;
    float* p = Z + (size_t)gm * COUT_ + n0 + txc;
#define ROW_EP(CA, CB, CC, CD, R)                                              \
    if (gm + R < NN) {                                                         \
      float z0 = CA + lb4.x, z1 = CB + lb4.y, z2 = CC + lb4.z, z3 = CD + lb4.w;\
      *(float4*)(p + R * COUT_) = make_float4(z0, z1, z2, z3);                 \
      ps0 += z0; ps1 += z1; ps2 += z2; ps3 += z3;                              \
      pq0 += z0 * z0; pq1 += z1 * z1; pq2 += z2 * z2; pq3 += z3 * z3;          \
    }
    ROW_EP(c00, c01, c02, c03, 0)
    ROW_EP(c10, c11, c12, c13, 1)
    ROW_EP(c20, c21, c22, c23, 2)
    ROW_EP(c30, c31, c32, c33, 3)
#undef ROW_EP
  }
  atomicAdd(&colS[txc + 0], ps0); atomicAdd(&colQ[txc + 0], pq0);
  atomicAdd(&colS[txc + 1], ps1); atomicAdd(&colQ[txc + 1], pq1);
  atomicAdd(&colS[txc + 2], ps2); atomicAdd(&colQ[txc + 2], pq2);
  atomicAdd(&colS[txc + 3], ps3); atomicAdd(&colQ[txc + 3], pq3);
  __syncthreads();
  if (t < 64) {
    atomicAdd(&gS[n0 + t], (double)colS[t]);
    atomicAdd(&gQ[n0 + t], (double)colQ[t]);
  }
}

// ---------------- BN finalize + accumulate into out ----------------
__global__ void k_bn(const float* __restrict__ Z, const double* __restrict__ gS,
                     const double* __restrict__ gQ, const float* __restrict__ gamma,
                     const float* __restrict__ beta, float* __restrict__ out) {
  int i = blockIdx.x * blockDim.x + threadIdx.x;
  if (i >= NN * COUT_) return;
  int cc = i & (COUT_ - 1);
  double mu = gS[cc] * (1.0 / NN);
  double var = gQ[cc] * (1.0 / NN) - mu * mu;
  float inv = (float)(1.0 / sqrt(var + 1e-5));
  out[i] += gamma[cc] * (Z[i] - (float)mu) * inv + beta[cc];
}

extern "C" void kernel_launch(void* const* d_in, const int* in_sizes, int n_in,
                              void* d_out, int out_size, void* d_ws, size_t ws_size,
                              hipStream_t stream) {
  const float* x     = (const float*)d_in[0];
  const int*   eiO   = (const int*)d_in[1];
  const float* Wg    = (const float*)d_in[2];
  const float* atts  = (const float*)d_in[3];
  const float* attd  = (const float*)d_in[4];
  const float* gb    = (const float*)d_in[5];
  const float* lw    = (const float*)d_in[6];
  const float* lb    = (const float*)d_in[7];
  const float* gamma = (const float*)d_in[8];
  const float* beta  = (const float*)d_in[9];
  const int*   sei[4] = {(const int*)d_in[10], (const int*)d_in[12],
                         (const int*)d_in[14], (const int*)d_in[16]};
  const float* sea[4] = {(const float*)d_in[11], (const float*)d_in[13],
                         (const float*)d_in[15], (const float*)d_in[17]};
  float* out = (float*)d_out;

  // ---- workspace carve (~205 MB) ----
  char* w = (char*)d_ws;
  auto take = [&](size_t bytes) -> void* {
    void* p = (void*)w;
    w += (bytes + 255) & ~(size_t)255;
    return p;
  };
  int*    rp0   = (int*)take((NN + 1) * sizeof(int));
  int*    nxt   = (int*)take(NN * sizeof(int));
  int*    cnt   = (int*)take(NN * sizeof(int));
  int*    srcS0 = (int*)take(EE * sizeof(int));
  float*  eaS0  = (float*)take(EE * sizeof(float));
  int*    rpT   = (int*)take((NN + 1) * sizeof(int));
  int*    srcST = (int*)take(EE * sizeof(int));
  float*  eaST  = (float*)take(EE * sizeof(float));
  int*    rpO   = (int*)take((NN + 1) * sizeof(int));
  int*    srcO  = (int*)take(EE * sizeof(int));
  float*  T     = (float*)take((size_t)NN * CIN_ * sizeof(float));
  float*  X     = (float*)take((size_t)NN * CIN_ * sizeof(float));
  float*  Hb    = (float*)take((size_t)NN * HC_ * sizeof(float));
  float*  G     = (float*)take((size_t)NN * HC_ * sizeof(float));
  float*  Z     = (float*)take((size_t)NN * COUT_ * sizeof(float));
  float*  ASb   = (float*)take((size_t)NN * 2 * sizeof(float));
  float*  ADb   = (float*)take((size_t)NN * 2 * sizeof(float));
  float*  Eb    = (float*)take((size_t)EE * 2 * sizeof(float));
  double* gS    = (double*)take(256 * sizeof(double));
  double* gQ    = gS + 128;

  const int EB = (EE + 255) / 256;   // edge-grid blocks
  const int NW = (NN + 3) / 4;       // node-wave blocks (4 waves of 64 per block)
  const int MB = (NN + 63) / 64;     // GEMM row tiles = 782

  (void)hipMemsetAsync(d_out, 0, (size_t)NN * COUT_ * sizeof(float), stream);

  // CSR for sei0 (reused 4x) and for edge_index_o (reused 4x)
  (void)hipMemsetAsync(cnt, 0, NN * sizeof(int), stream);
  k_hist<<<EB, 256, 0, stream>>>(sei[0] + EE, cnt);
  k_scan<<<1, 1024, 0, stream>>>(cnt, rp0, nxt, NN);
  k_fill<<<EB, 256, 0, stream>>>(sei[0], sei[0] + EE, sea[0], nxt, srcS0, eaS0);

  (void)hipMemsetAsync(cnt, 0, NN * sizeof(int), stream);
  k_hist<<<EB, 256, 0, stream>>>(eiO + EE, cnt);
  k_scan<<<1, 1024, 0, stream>>>(cnt, rpO, nxt, NN);
  k_fill<<<EB, 256, 0, stream>>>(eiO, eiO + EE, (const float*)nullptr, nxt, srcO, (float*)nullptr);

  for (int g = 0; g < 4; ++g) {
    if (g == 0) {
      k_solo<<<NW, 256, 0, stream>>>(rp0, srcS0, eaS0, x, X);
    } else {
      (void)hipMemsetAsync(cnt, 0, NN * sizeof(int), stream);
      k_hist<<<EB, 256, 0, stream>>>(sei[g] + EE, cnt);
      k_scan<<<1, 1024, 0, stream>>>(cnt, rpT, nxt, NN);
      k_fill<<<EB, 256, 0, stream>>>(sei[g], sei[g] + EE, sea[g], nxt, srcST, eaST);
      k_solo<<<NW, 256, 0, stream>>>(rpT, srcST, eaST, x, T);   // xh_g = S_g(x)
      k_solo<<<NW, 256, 0, stream>>>(rp0, srcS0, eaS0, T, X);   // x_g = S_0(xh_g)
    }
    k_gemm1<<<dim3(MB, 4), 256, 0, stream>>>(X, Wg + (size_t)g * CIN_ * HC_, Hb);
    k_attn<<<NW, 256, 0, stream>>>(Hb, atts + (size_t)g * HC_, attd + (size_t)g * HC_, ASb, ADb);
    k_gat<<<NW, 256, 0, stream>>>(rpO, srcO, ASb, ADb, Hb, Eb, G);
    (void)hipMemsetAsync(gS, 0, 256 * sizeof(double), stream);
    k_gemm2<<<dim3(MB, 2), 256, 0, stream>>>(G, gb + (size_t)g * HC_,
                                             lw + (size_t)g * HC_ * COUT_,
                                             lb + (size_t)g * COUT_, Z, gS, gQ);
    k_bn<<<(NN * COUT_ + 255) / 256, 256, 0, stream>>>(Z, gS, gQ,
                                                       gamma + (size_t)g * COUT_,
                                                       beta + (size_t)g * COUT_, out);
  }
}